// Round 2
// baseline (1034.166 us; speedup 1.0000x reference)
//
#include <hip/hip_runtime.h>

// RGCN block-diagonal layer, f32.
// out = relu( (scatter_sum(msg) * norm) + bias + h @ loop_weight )
// msg[e, b*16+o] = sum_i h[src[e], b*16+i] * W[type[e], b*256 + i*16 + o]
//
// Pipeline:
//   Z: zero hist/cursor in ws
//   H: histogram edge types (16 bins)
//   S: exclusive scan -> cursor
//   C: counting-sort scatter edges into type-sorted order (ws)
//   A: init_kernel : out[n][:] = bias + h[n] @ loop_weight  (LDS-staged LW)
//   B: edge_sorted : out[dst][:] += msg * norm[dst], weights in REGISTERS
//   R: relu
//
// ws layout: [0..15] ghist, [16..31] cursor, [64..] ssrc[E], sdst[E], stype[E]

__global__ __launch_bounds__(256) void rgcn_init_kernel(
    const float* __restrict__ h, const float* __restrict__ loop_w,
    const float* __restrict__ bias, float* __restrict__ out, int N) {
  __shared__ float lw[128 * 128];  // 64 KB
  for (int idx = threadIdx.x; idx < 128 * 128 / 4; idx += 256) {
    ((float4*)lw)[idx] = ((const float4*)loop_w)[idx];
  }
  __syncthreads();

  const int lane = threadIdx.x & 63;
  const int wid = threadIdx.x >> 6;
  const int group0 = blockIdx.x * 4 + wid;
  const int ngroups = gridDim.x * 4;
  const int totgroups = (N + 3) >> 2;
  const float b0 = bias[lane];
  const float b1 = bias[64 + lane];

  for (int g = group0; g < totgroups; g += ngroups) {
    const int n0 = g * 4;
    const int nn = (N - n0 < 4) ? (N - n0) : 4;
    if (nn == 4) {
      const float* __restrict__ r0 = h + (size_t)n0 * 128;
      const float* __restrict__ r1 = r0 + 128;
      const float* __restrict__ r2 = r1 + 128;
      const float* __restrict__ r3 = r2 + 128;
      float a00 = b0, a01 = b1, a10 = b0, a11 = b1;
      float a20 = b0, a21 = b1, a30 = b0, a31 = b1;
#pragma unroll 4
      for (int k = 0; k < 128; ++k) {
        const float w0 = lw[k * 128 + lane];
        const float w1 = lw[k * 128 + 64 + lane];
        a00 = fmaf(r0[k], w0, a00); a01 = fmaf(r0[k], w1, a01);
        a10 = fmaf(r1[k], w0, a10); a11 = fmaf(r1[k], w1, a11);
        a20 = fmaf(r2[k], w0, a20); a21 = fmaf(r2[k], w1, a21);
        a30 = fmaf(r3[k], w0, a30); a31 = fmaf(r3[k], w1, a31);
      }
      float* __restrict__ o0 = out + (size_t)n0 * 128;
      o0[lane] = a00;        o0[64 + lane] = a01;
      o0[128 + lane] = a10;  o0[192 + lane] = a11;
      o0[256 + lane] = a20;  o0[320 + lane] = a21;
      o0[384 + lane] = a30;  o0[448 + lane] = a31;
    } else {
      for (int r = 0; r < nn; ++r) {
        const int n = n0 + r;
        const float* __restrict__ hr = h + (size_t)n * 128;
        float a0 = b0, a1 = b1;
#pragma unroll 4
        for (int k = 0; k < 128; ++k) {
          const float a = hr[k];
          a0 = fmaf(a, lw[k * 128 + lane], a0);
          a1 = fmaf(a, lw[k * 128 + 64 + lane], a1);
        }
        out[(size_t)n * 128 + lane] = a0;
        out[(size_t)n * 128 + 64 + lane] = a1;
      }
    }
  }
}

__global__ void rgcn_zero_kernel(int* __restrict__ p) {
  if (threadIdx.x < 32) p[threadIdx.x] = 0;
}

__global__ __launch_bounds__(256) void rgcn_hist_kernel(
    const int* __restrict__ etype, int* __restrict__ ghist, int E) {
  __shared__ int lh[16];
  if (threadIdx.x < 16) lh[threadIdx.x] = 0;
  __syncthreads();
  for (int e = blockIdx.x * 256 + threadIdx.x; e < E; e += gridDim.x * 256)
    atomicAdd(&lh[etype[e]], 1);
  __syncthreads();
  if (threadIdx.x < 16) atomicAdd(&ghist[threadIdx.x], lh[threadIdx.x]);
}

__global__ void rgcn_scan_kernel(const int* __restrict__ ghist,
                                 int* __restrict__ cursor) {
  if (threadIdx.x == 0) {
    int run = 0;
    for (int t = 0; t < 16; ++t) {
      cursor[t] = run;
      run += ghist[t];
    }
  }
}

__global__ __launch_bounds__(256) void rgcn_scatter_kernel(
    const int* __restrict__ esrc, const int* __restrict__ edst,
    const int* __restrict__ etype, int* __restrict__ cursor,
    int* __restrict__ ssrc, int* __restrict__ sdst, int* __restrict__ stype,
    int E, int EPB) {
  __shared__ int lh[16];
  __shared__ int lbase[16];
  const int b0 = blockIdx.x * EPB;
  const int b1 = min(E, b0 + EPB);
  if (threadIdx.x < 16) lh[threadIdx.x] = 0;
  __syncthreads();
  for (int e = b0 + threadIdx.x; e < b1; e += 256) atomicAdd(&lh[etype[e]], 1);
  __syncthreads();
  if (threadIdx.x < 16) {
    lbase[threadIdx.x] = atomicAdd(&cursor[threadIdx.x], lh[threadIdx.x]);
    lh[threadIdx.x] = 0;
  }
  __syncthreads();
  for (int e = b0 + threadIdx.x; e < b1; e += 256) {
    const int t = etype[e];
    const int r = atomicAdd(&lh[t], 1);
    const int p = lbase[t] + r;
    ssrc[p] = esrc[e];
    sdst[p] = edst[e];
    stype[p] = t;
  }
}

// Edge kernel over type-sorted edges: relation weights live in registers
// (32 VGPR/lane = the full 8 KB block across the wave), reloaded only at
// type boundaries (15 times across the whole edge list).
__global__ __launch_bounds__(256) void rgcn_edge_sorted_kernel(
    const float* __restrict__ h, const float* __restrict__ norm,
    const int* __restrict__ ssrc, const int* __restrict__ sdst,
    const int* __restrict__ stype, const float* __restrict__ weight,
    float* __restrict__ out, int E, int chunk) {
  const int lane = threadIdx.x & 63;
  const int wid = blockIdx.x * 4 + (threadIdx.x >> 6);
  const int b = lane >> 4;  // block 0..3 (lo half); hi half uses b+4
  const int o = lane & 15;  // output col within block

  long e0 = (long)wid * chunk;
  if (e0 >= E) return;
  long e1 = e0 + chunk;
  if (e1 > E) e1 = E;

  int cur = -1;
  float wlo[16], whi[16];

  for (long e = e0; e < e1; ++e) {
    const int t = stype[e];
    if (t != cur) {
      cur = t;
      const float* __restrict__ wb = weight + t * 2048 + b * 256 + o;
#pragma unroll
      for (int i = 0; i < 16; ++i) {
        wlo[i] = wb[i * 16];
        whi[i] = wb[1024 + i * 16];
      }
    }
    const int src = ssrc[e];
    const int dst = sdst[e];
    const float nrm = norm[dst];

    // broadcast float4 loads of this lane's two 16-wide input blocks
    const float4* __restrict__ hp =
        (const float4*)(h + (size_t)src * 128) + b * 4;
    const float4 x0 = hp[0], x1 = hp[1], x2 = hp[2], x3 = hp[3];
    const float4 y0 = hp[16], y1 = hp[17], y2 = hp[18], y3 = hp[19];

    float a0 = x0.x * wlo[0], a1 = x0.y * wlo[1];
    a0 = fmaf(x0.z, wlo[2], a0);  a1 = fmaf(x0.w, wlo[3], a1);
    a0 = fmaf(x1.x, wlo[4], a0);  a1 = fmaf(x1.y, wlo[5], a1);
    a0 = fmaf(x1.z, wlo[6], a0);  a1 = fmaf(x1.w, wlo[7], a1);
    a0 = fmaf(x2.x, wlo[8], a0);  a1 = fmaf(x2.y, wlo[9], a1);
    a0 = fmaf(x2.z, wlo[10], a0); a1 = fmaf(x2.w, wlo[11], a1);
    a0 = fmaf(x3.x, wlo[12], a0); a1 = fmaf(x3.y, wlo[13], a1);
    a0 = fmaf(x3.z, wlo[14], a0); a1 = fmaf(x3.w, wlo[15], a1);

    float c0 = y0.x * whi[0], c1 = y0.y * whi[1];
    c0 = fmaf(y0.z, whi[2], c0);  c1 = fmaf(y0.w, whi[3], c1);
    c0 = fmaf(y1.x, whi[4], c0);  c1 = fmaf(y1.y, whi[5], c1);
    c0 = fmaf(y1.z, whi[6], c0);  c1 = fmaf(y1.w, whi[7], c1);
    c0 = fmaf(y2.x, whi[8], c0);  c1 = fmaf(y2.y, whi[9], c1);
    c0 = fmaf(y2.z, whi[10], c0); c1 = fmaf(y2.w, whi[11], c1);
    c0 = fmaf(y3.x, whi[12], c0); c1 = fmaf(y3.y, whi[13], c1);
    c0 = fmaf(y3.z, whi[14], c0); c1 = fmaf(y3.w, whi[15], c1);

    atomicAdd(&out[(size_t)dst * 128 + lane], (a0 + a1) * nrm);
    atomicAdd(&out[(size_t)dst * 128 + 64 + lane], (c0 + c1) * nrm);
  }
}

// Fallback (ws too small): round-1 unsorted edge kernel with weight loads.
__global__ __launch_bounds__(256) void rgcn_edge_kernel(
    const float* __restrict__ h, const float* __restrict__ norm,
    const int* __restrict__ esrc, const int* __restrict__ edst,
    const int* __restrict__ etype, const float* __restrict__ weight,
    float* __restrict__ out, int E) {
  const int lane = threadIdx.x & 63;
  const int wid = threadIdx.x >> 6;
  const int wave0 = blockIdx.x * 4 + wid;
  const int nwaves = gridDim.x * 4;
  const int b = lane >> 4;
  const int o = lane & 15;

  for (int e = wave0; e < E; e += nwaves) {
    const int src = esrc[e];
    const int dst = edst[e];
    const int et = etype[e];
    const float s_lo = h[src * 128 + lane];
    const float s_hi = h[src * 128 + 64 + lane];
    const float nrm = norm[dst];
    const float* __restrict__ Wb = weight + et * 2048 + b * 256 + o;
    float m0 = 0.f, m1 = 0.f;
#pragma unroll
    for (int i = 0; i < 16; ++i) {
      const float a_lo = __shfl(s_lo, (lane & 48) + i, 64);
      const float a_hi = __shfl(s_hi, (lane & 48) + i, 64);
      m0 = fmaf(a_lo, Wb[i * 16], m0);
      m1 = fmaf(a_hi, Wb[1024 + i * 16], m1);
    }
    atomicAdd(&out[dst * 128 + lane], m0 * nrm);
    atomicAdd(&out[dst * 128 + 64 + lane], m1 * nrm);
  }
}

__global__ __launch_bounds__(256) void rgcn_relu_kernel(float* __restrict__ out,
                                                        int total4) {
  int i = blockIdx.x * 256 + threadIdx.x;
  const int stride = gridDim.x * 256;
  for (; i < total4; i += stride) {
    float4 v = ((float4*)out)[i];
    v.x = fmaxf(v.x, 0.f);
    v.y = fmaxf(v.y, 0.f);
    v.z = fmaxf(v.z, 0.f);
    v.w = fmaxf(v.w, 0.f);
    ((float4*)out)[i] = v;
  }
}

extern "C" void kernel_launch(void* const* d_in, const int* in_sizes, int n_in,
                              void* d_out, int out_size, void* d_ws, size_t ws_size,
                              hipStream_t stream) {
  const float* h      = (const float*)d_in[0];
  const float* norm   = (const float*)d_in[1];
  const int*   esrc   = (const int*)d_in[2];
  const int*   edst   = (const int*)d_in[3];
  const int*   etype  = (const int*)d_in[4];
  const float* weight = (const float*)d_in[5];
  const float* bias   = (const float*)d_in[6];
  const float* loop_w = (const float*)d_in[7];
  float* out = (float*)d_out;

  const int N = in_sizes[0] / 128;
  const int E = in_sizes[2];

  rgcn_init_kernel<<<2048, 256, 0, stream>>>(h, loop_w, bias, out, N);

  const size_t need = 256 + 12ull * (size_t)E;
  if (ws_size >= need) {
    int* ghist  = (int*)d_ws;
    int* cursor = ghist + 16;
    int* ssrc   = ghist + 64;
    int* sdst   = ssrc + E;
    int* stype  = sdst + E;

    rgcn_zero_kernel<<<1, 64, 0, stream>>>(ghist);
    rgcn_hist_kernel<<<1024, 256, 0, stream>>>(etype, ghist, E);
    rgcn_scan_kernel<<<1, 64, 0, stream>>>(ghist, cursor);
    const int EPB = 4096;
    rgcn_scatter_kernel<<<(E + EPB - 1) / EPB, 256, 0, stream>>>(
        esrc, edst, etype, cursor, ssrc, sdst, stype, E, EPB);

    const int nwaves = 4096 * 4;
    const int chunk = (E + nwaves - 1) / nwaves;
    rgcn_edge_sorted_kernel<<<4096, 256, 0, stream>>>(
        h, norm, ssrc, sdst, stype, weight, out, E, chunk);
  } else {
    rgcn_edge_kernel<<<4096, 256, 0, stream>>>(h, norm, esrc, edst, etype,
                                               weight, out, E);
  }

  rgcn_relu_kernel<<<2048, 256, 0, stream>>>(out, (N * 128) / 4);
}